// Round 10
// baseline (313.048 us; speedup 1.0000x reference)
//
#include <hip/hip_runtime.h>

#define NN 50000
#define EE 600000
#define INF 256
#define HF 128
#define CEB ((EE + 255) / 256)   // 2344 blocks for edge-parallel work
#define GBK ((NN + 63) / 64)     // 782 gemm blocks

typedef __attribute__((ext_vector_type(8))) short short8;
typedef __attribute__((ext_vector_type(4))) float floatx4;

// ---------------- bf16 helpers ----------------
__device__ __forceinline__ unsigned short f32_to_bf16_rne(float x) {
    unsigned int u = __float_as_uint(x);
    unsigned int r = (u + 0x7FFFu + ((u >> 16) & 1u)) >> 16;
    return (unsigned short)r;
}
__device__ __forceinline__ float bf16_to_f32(unsigned short h) {
    return __uint_as_float(((unsigned int)h) << 16);
}
__device__ __forceinline__ float bf16lo_u32(unsigned int u) {
    return __uint_as_float(u << 16);
}
__device__ __forceinline__ float bf16hi_u32(unsigned int u) {
    return __uint_as_float(u & 0xFFFF0000u);
}
__device__ __forceinline__ void cvt_hilo8(float4 v0, float4 v1, short8& hs, short8& ls) {
    float x[8] = {v0.x, v0.y, v0.z, v0.w, v1.x, v1.y, v1.z, v1.w};
    union { short8 s; unsigned short u[8]; } H, L;
#pragma unroll
    for (int k = 0; k < 8; ++k) {
        unsigned short hi = f32_to_bf16_rne(x[k]);
        H.u[k] = hi;
        L.u[k] = f32_to_bf16_rne(x[k] - bf16_to_f32(hi));
    }
    hs = H.s;
    ls = L.s;
}

// ---------------- fused: degree counting (saving per-edge rank) + weight prepack -------
__global__ void count_and_prepack(const int* __restrict__ row, int* __restrict__ cnt,
                                  int* __restrict__ pos, int E,
                                  const float* __restrict__ lw, const float* __restrict__ cw,
                                  unsigned short* __restrict__ fl, unsigned short* __restrict__ fc) {
    int b = blockIdx.x;
    if (b < CEB) {
        int e = b * 256 + threadIdx.x;
        if (e < E) pos[e] = atomicAdd(&cnt[row[e]], 1);
        return;
    }
    int idx = (b - CEB) * 256 + threadIdx.x;
    const float* src;
    unsigned short* dst;
    int K, c;
    if (idx < 8192) {
        src = lw; dst = fl; K = INF; c = idx;
    } else if (idx < 12288) {
        src = cw; dst = fc; K = HF; c = idx - 8192;
    } else return;
    int lane = c & 63;
    int nt = (c >> 6) & 7;
    int hl = (c >> 9) & 1;
    int kc = c >> 10;
    int rw = nt * 16 + (lane & 15);
    int koff = kc * 32 + (lane >> 4) * 8;
    const float* p = &src[(size_t)rw * K + koff];
    float4 v0 = *reinterpret_cast<const float4*>(p);
    float4 v1 = *reinterpret_cast<const float4*>(p + 4);
    short8 hs, ls;
    cvt_hilo8(v0, v1, hs, ls);
    *reinterpret_cast<short8*>(&dst[(size_t)c * 8]) = hl ? ls : hs;
}

// ---------------- scan phase1: per-block sums of cnt ----------------
__global__ void scan_phase1(const int* __restrict__ cnt, int* __restrict__ bsum, int n) {
    __shared__ int sdata[256];
    int t = threadIdx.x;
    int i = blockIdx.x * 256 + t;
    sdata[t] = (i < n) ? cnt[i] : 0;
    __syncthreads();
    for (int s = 128; s > 0; s >>= 1) {
        if (t < s) sdata[t] += sdata[t + s];
        __syncthreads();
    }
    if (t == 0) bsum[blockIdx.x] = sdata[0];
}

// ---------------- scan phase2+3 fused (+ finalize_deg) ----------------
__global__ void scan_phase3(const int* __restrict__ cnt, const int* __restrict__ bsum,
                            int* __restrict__ row_start,
                            float* __restrict__ deg_inv, float* __restrict__ dis,
                            int n, int nb, int E) {
    __shared__ int sb[256];
    __shared__ int sdata[256];
    int t = threadIdx.x;
    sb[t] = (t < nb) ? bsum[t] : 0;
    __syncthreads();
    for (int s = 1; s < 256; s <<= 1) {
        int add = (t >= s) ? sb[t - s] : 0;
        __syncthreads();
        sb[t] += add;
        __syncthreads();
    }
    int base = sb[blockIdx.x] - bsum[blockIdx.x];
    int i = blockIdx.x * 256 + t;
    int v = (i < n) ? cnt[i] : 0;
    sdata[t] = v;
    __syncthreads();
    for (int s = 1; s < 256; s <<= 1) {
        int add = (t >= s) ? sdata[t - s] : 0;
        __syncthreads();
        sdata[t] += add;
        __syncthreads();
    }
    if (i < n) {
        int ex = base + sdata[t] - v;
        row_start[i] = ex;
        float d = (float)(v + 1);
        deg_inv[i] = 1.0f / d;
        dis[i] = rsqrtf(d);
    }
    if (blockIdx.x == 0 && t == 0) row_start[n] = E;
}

// ---------------- split-bf16 MFMA GEMM, W staged in LDS in 32KB chunks ----------------
// Cbf now split into two N*64 half-arrays (hbfA feats 0-63, hbfB 64-127) for the
// 2-pass aggregate's L2 residency. FILL=true: blocks [GBK, GBK+CEB) run the atomic-free
// CSR fill instead (overlaps scatter latency with MFMA compute).
template <int K, int MODE, bool FILL>
__global__ __launch_bounds__(256) void gemm_ldsw(
    const float* __restrict__ Af,
    const unsigned short* __restrict__ Ahg, const unsigned short* __restrict__ Alg,
    const unsigned short* __restrict__ Wf,
    const float* __restrict__ bias,
    float* __restrict__ C,
    unsigned short* __restrict__ hbfA, unsigned short* __restrict__ hbfB,
    const float* __restrict__ h, const float* __restrict__ deg_inv,
    const float* __restrict__ dis, const float* __restrict__ root,
    const float* __restrict__ gamma, const float* __restrict__ beta,
    int M,
    const int* __restrict__ erow, const int* __restrict__ ecol,
    const int* __restrict__ row_start, const int* __restrict__ pos,
    int* __restrict__ csr_col, int E) {
    constexpr int NKC = K / 32;
    __shared__ unsigned short WS[2 * 8192];   // 2 kc x 16KB = 32KB

    if (FILL && blockIdx.x >= GBK) {
        int e = (blockIdx.x - GBK) * 256 + threadIdx.x;
        if (e < E) {
            int p = row_start[erow[e]] + pos[e];
            __builtin_nontemporal_store(ecol[e], &csr_col[p]);
        }
        return;
    }

    const int t = threadIdx.x;
    const int wave = t >> 6;
    const int lane = t & 63;
    const int lrow = lane & 15;
    const int quad = lane >> 4;
    const int bm = blockIdx.x * 64;
    int arow = bm + wave * 16 + lrow;
    if (arow >= M) arow = M - 1;   // clamp; stores are predicated

    floatx4 acc[8];
#pragma unroll
    for (int nt = 0; nt < 8; ++nt) acc[nt] = (floatx4){0.f, 0.f, 0.f, 0.f};

#pragma unroll
    for (int p = 0; p < NKC / 2; ++p) {
        if (p) __syncthreads();
        {
            const uint4* src = reinterpret_cast<const uint4*>(Wf + (size_t)p * 16384);
            uint4* dstl = reinterpret_cast<uint4*>(WS);
#pragma unroll
            for (int i = 0; i < 8; ++i) dstl[t + 256 * i] = src[t + 256 * i];
        }
        __syncthreads();
#pragma unroll
        for (int k2 = 0; k2 < 2; ++k2) {
            int kc = p * 2 + k2;
            short8 afh, afl;
            if (MODE == 0) {
                const float* ap = &Af[(size_t)arow * K + kc * 32 + quad * 8];
                float4 a0 = *reinterpret_cast<const float4*>(ap);
                float4 a1 = *reinterpret_cast<const float4*>(ap + 4);
                cvt_hilo8(a0, a1, afh, afl);
            } else {
                size_t ao = (size_t)arow * K + kc * 32 + quad * 8;
                afh = *reinterpret_cast<const short8*>(&Ahg[ao]);
                afl = *reinterpret_cast<const short8*>(&Alg[ao]);
            }
            const unsigned short* wb = &WS[k2 * 8192 + lane * 8];
#pragma unroll
            for (int nt = 0; nt < 8; ++nt) {
                short8 bfh = *reinterpret_cast<const short8*>(wb + nt * 512);
                short8 bfl = *reinterpret_cast<const short8*>(wb + 4096 + nt * 512);
                acc[nt] = __builtin_amdgcn_mfma_f32_16x16x32_bf16(afh, bfh, acc[nt], 0, 0, 0);
                acc[nt] = __builtin_amdgcn_mfma_f32_16x16x32_bf16(afl, bfh, acc[nt], 0, 0, 0);
                acc[nt] = __builtin_amdgcn_mfma_f32_16x16x32_bf16(afh, bfl, acc[nt], 0, 0, 0);
            }
        }
    }

    float cb[8], rt[8], gm[8], bt[8];
#pragma unroll
    for (int nt = 0; nt < 8; ++nt) {
        int colh = nt * 16 + lrow;
        cb[nt] = bias[colh];
        if (MODE >= 1) rt[nt] = root[colh];
        if (MODE == 1) { gm[nt] = gamma[colh]; bt[nt] = beta[colh]; }
    }

#pragma unroll
    for (int r = 0; r < 4; ++r) {
        int grow = bm + wave * 16 + quad * 4 + r;
        bool ok = (grow < M);
        int gr = ok ? grow : M - 1;
        float x[8];
        if (MODE == 0) {
#pragma unroll
            for (int nt = 0; nt < 8; ++nt) x[nt] = acc[nt][r] + cb[nt];
        } else {
            float di = deg_inv[gr];
            float hv[8];
#pragma unroll
            for (int nt = 0; nt < 8; ++nt) hv[nt] = h[(size_t)gr * HF + nt * 16 + lrow];
#pragma unroll
            for (int nt = 0; nt < 8; ++nt) {
                float v = acc[nt][r] + cb[nt] + fmaxf(hv[nt] + rt[nt], 0.f) * di;
                x[nt] = (MODE == 1) ? v + hv[nt] : v;
            }
        }
        if (MODE == 1) {
            float s = 0.f;
#pragma unroll
            for (int nt = 0; nt < 8; ++nt) s += x[nt];
#pragma unroll
            for (int m = 1; m < 16; m <<= 1) s += __shfl_xor(s, m, 64);
            float mu = s * (1.0f / HF);
            float var = 0.f;
#pragma unroll
            for (int nt = 0; nt < 8; ++nt) { float d = x[nt] - mu; var += d * d; }
#pragma unroll
            for (int m = 1; m < 16; m <<= 1) var += __shfl_xor(var, m, 64);
            float rs = rsqrtf(var * (1.0f / HF) + 1e-5f);
            float ds = dis[gr];
            if (ok) {
#pragma unroll
                for (int nt = 0; nt < 8; ++nt) {
                    int colh = nt * 16 + lrow;
                    float y = fmaxf((x[nt] - mu) * rs * gm[nt] + bt[nt], 0.f);
                    C[(size_t)grow * HF + colh] = y;
                    unsigned short* half = (nt < 4) ? hbfA : hbfB;
                    half[(size_t)grow * 64 + (nt & 3) * 16 + lrow] = f32_to_bf16_rne(ds * y);
                }
            }
        } else if (MODE == 0) {
            if (ok) {
                float ds = dis[grow];
#pragma unroll
                for (int nt = 0; nt < 8; ++nt) {
                    int colh = nt * 16 + lrow;
                    C[(size_t)grow * HF + colh] = x[nt];
                    unsigned short* half = (nt < 4) ? hbfA : hbfB;
                    half[(size_t)grow * 64 + (nt & 3) * 16 + lrow] = f32_to_bf16_rne(ds * x[nt]);
                }
            }
        } else {
            if (ok) {
#pragma unroll
                for (int nt = 0; nt < 8; ++nt)
                    C[(size_t)grow * HF + nt * 16 + lrow] = x[nt];
            }
        }
    }
}

// ---------------- aggregate, feature-split into 2 passes for per-XCD L2 residency ------
// PASS p gathers from 6.4MB half-array hbfH (feats p*64..p*64+63); agg written into the
// shared N*128 hi/lo arrays at column offset p*64. Quarter-wave per edge, fast path
// deg<=16 (predicated, 16 gathers in flight), slow loop otherwise. Lane covers 4 feats.
template <int PASS>
__global__ void aggregate_half(const int* __restrict__ row_start, const int* __restrict__ csr_col,
                               const float* __restrict__ dis, const float* __restrict__ deg_inv,
                               const float* __restrict__ h, const unsigned short* __restrict__ hbfH,
                               unsigned short* __restrict__ agg_hi, unsigned short* __restrict__ agg_lo,
                               int n) {
    int wid = (blockIdx.x * blockDim.x + threadIdx.x) >> 6;
    int lane = threadIdx.x & 63;
    if (wid >= n) return;
    int q = lane >> 4;
    int l16 = lane & 15;
    int s = row_start[wid];
    int e = row_start[wid + 1];
    float a0 = 0.f, a1 = 0.f, a2 = 0.f, a3 = 0.f;
    if (e - s <= 16) {
        int j0 = s + q;
        bool p0 = j0 < e, p1 = j0 + 4 < e, p2 = j0 + 8 < e, p3 = j0 + 12 < e;
        int c0 = p0 ? csr_col[j0] : 0;
        int c1 = p1 ? csr_col[j0 + 4] : 0;
        int c2 = p2 ? csr_col[j0 + 8] : 0;
        int c3 = p3 ? csr_col[j0 + 12] : 0;
        uint2 z = make_uint2(0, 0);
        uint2 g0 = z, g1 = z, g2 = z, g3 = z;
        if (p0) g0 = *reinterpret_cast<const uint2*>(&hbfH[(size_t)c0 * 64 + l16 * 4]);
        if (p1) g1 = *reinterpret_cast<const uint2*>(&hbfH[(size_t)c1 * 64 + l16 * 4]);
        if (p2) g2 = *reinterpret_cast<const uint2*>(&hbfH[(size_t)c2 * 64 + l16 * 4]);
        if (p3) g3 = *reinterpret_cast<const uint2*>(&hbfH[(size_t)c3 * 64 + l16 * 4]);
        a0 = bf16lo_u32(g0.x) + bf16lo_u32(g1.x) + bf16lo_u32(g2.x) + bf16lo_u32(g3.x);
        a1 = bf16hi_u32(g0.x) + bf16hi_u32(g1.x) + bf16hi_u32(g2.x) + bf16hi_u32(g3.x);
        a2 = bf16lo_u32(g0.y) + bf16lo_u32(g1.y) + bf16lo_u32(g2.y) + bf16lo_u32(g3.y);
        a3 = bf16hi_u32(g0.y) + bf16hi_u32(g1.y) + bf16hi_u32(g2.y) + bf16hi_u32(g3.y);
    } else {
        float b0 = 0.f, b1 = 0.f, b2 = 0.f, b3 = 0.f;
        int j = s + q;
        for (; j + 4 < e; j += 8) {
            int c0 = csr_col[j];
            int c1 = csr_col[j + 4];
            uint2 g0 = *reinterpret_cast<const uint2*>(&hbfH[(size_t)c0 * 64 + l16 * 4]);
            uint2 g1 = *reinterpret_cast<const uint2*>(&hbfH[(size_t)c1 * 64 + l16 * 4]);
            a0 += bf16lo_u32(g0.x); a1 += bf16hi_u32(g0.x);
            a2 += bf16lo_u32(g0.y); a3 += bf16hi_u32(g0.y);
            b0 += bf16lo_u32(g1.x); b1 += bf16hi_u32(g1.x);
            b2 += bf16lo_u32(g1.y); b3 += bf16hi_u32(g1.y);
        }
        if (j < e) {
            int c0 = csr_col[j];
            uint2 g0 = *reinterpret_cast<const uint2*>(&hbfH[(size_t)c0 * 64 + l16 * 4]);
            a0 += bf16lo_u32(g0.x); a1 += bf16hi_u32(g0.x);
            a2 += bf16lo_u32(g0.y); a3 += bf16hi_u32(g0.y);
        }
        a0 += b0; a1 += b1; a2 += b2; a3 += b3;
    }
#pragma unroll
    for (int m = 16; m < 64; m <<= 1) {
        a0 += __shfl_xor(a0, m, 64);
        a1 += __shfl_xor(a1, m, 64);
        a2 += __shfl_xor(a2, m, 64);
        a3 += __shfl_xor(a3, m, 64);
    }
    if (q == 0) {
        float dn = dis[wid];
        float di = deg_inv[wid];
        float4 hv = *reinterpret_cast<const float4*>(&h[(size_t)wid * HF + PASS * 64 + l16 * 4]);
        float o[4];
        o[0] = fmaf(dn, a0, di * hv.x);
        o[1] = fmaf(dn, a1, di * hv.y);
        o[2] = fmaf(dn, a2, di * hv.z);
        o[3] = fmaf(dn, a3, di * hv.w);
        ushort4 hp, lp;
        unsigned short* hpp = &hp.x;
        unsigned short* lpp = &lp.x;
#pragma unroll
        for (int k = 0; k < 4; ++k) {
            unsigned short hi = f32_to_bf16_rne(o[k]);
            hpp[k] = hi;
            lpp[k] = f32_to_bf16_rne(o[k] - bf16_to_f32(hi));
        }
        *reinterpret_cast<ushort4*>(&agg_hi[(size_t)wid * HF + PASS * 64 + l16 * 4]) = hp;
        *reinterpret_cast<ushort4*>(&agg_lo[(size_t)wid * HF + PASS * 64 + l16 * 4]) = lp;
    }
}

extern "C" void kernel_launch(void* const* d_in, const int* in_sizes, int n_in,
                              void* d_out, int out_size, void* d_ws, size_t ws_size,
                              hipStream_t stream) {
    const int N = NN, E = EE;
    const float* in_feat = (const float*)d_in[0];
    const int* row = (const int*)d_in[1];
    const int* col = (const int*)d_in[2];
    const float* lin_w = (const float*)d_in[3];
    const float* lin_b = (const float*)d_in[4];
    const float* conv_w = (const float*)d_in[5];
    const float* conv_b = (const float*)d_in[6];
    const float* root_emb = (const float*)d_in[7];
    const float* ln_gamma = (const float*)d_in[8];
    const float* ln_beta = (const float*)d_in[9];
    float* out = (float*)d_out;

    // workspace layout (4B units); all segments kept 16B-aligned
    float* ws = (float*)d_ws;
    size_t o = 0;
    float* deg_inv = ws + o; o += N;
    float* dis = ws + o; o += N;
    int* cnt = (int*)(ws + o); o += N;
    int* row_start = (int*)(ws + o); o += N + 4;
    int* pos = (int*)(ws + o); o += E;
    int* bsum = (int*)(ws + o); o += 256;
    int* csr_col = (int*)(ws + o); o += E;
    o = (o + 3) & ~(size_t)3;
    unsigned short* fl = (unsigned short*)(ws + o); o += 32768;  // 65536 ushort (128KB)
    unsigned short* fc = (unsigned short*)(ws + o); o += 16384;  // 32768 ushort (64KB)
    float* h0 = ws + o; o += (size_t)N * HF;
    unsigned short* hbfA = (unsigned short*)(ws + o); o += (size_t)N * 32;  // N*64 ushort
    unsigned short* hbfB = (unsigned short*)(ws + o); o += (size_t)N * 32;
    unsigned short* agg_hi = (unsigned short*)(ws + o); o += (size_t)N * HF / 2;
    unsigned short* agg_lo = (unsigned short*)(ws + o); o += (size_t)N * HF / 2;

    const int NB = (N + 255) / 256;   // 196

    hipMemsetAsync(cnt, 0, N * sizeof(int), stream);
    count_and_prepack<<<CEB + 48, 256, 0, stream>>>(row, cnt, pos, E, lin_w, conv_w, fl, fc);
    scan_phase1<<<NB, 256, 0, stream>>>(cnt, bsum, N);
    scan_phase3<<<NB, 256, 0, stream>>>(cnt, bsum, row_start, deg_inv, dis, N, NB, E);

    const int WB = (N + 3) / 4;

    // lin gemm (blocks [0,GBK)) + CSR fill (blocks [GBK,GBK+CEB)) in one dispatch
    gemm_ldsw<INF, 0, true><<<GBK + CEB, 256, 0, stream>>>(
        in_feat, nullptr, nullptr, fl, lin_b, h0, hbfA, hbfB,
        nullptr, nullptr, dis, nullptr, nullptr, nullptr, N,
        row, col, row_start, pos, csr_col, E);

    // ---- prop step 0 (2-pass aggregate, conv + fused residual/LN/ReLU -> h0) ----
    aggregate_half<0><<<WB, 256, 0, stream>>>(row_start, csr_col, dis, deg_inv, h0, hbfA,
                                              agg_hi, agg_lo, N);
    aggregate_half<1><<<WB, 256, 0, stream>>>(row_start, csr_col, dis, deg_inv, h0, hbfB,
                                              agg_hi, agg_lo, N);
    gemm_ldsw<HF, 1, false><<<GBK, 256, 0, stream>>>(
        nullptr, agg_hi, agg_lo, fc, conv_b, h0, hbfA, hbfB,
        h0, deg_inv, dis, root_emb, ln_gamma + HF, ln_beta + HF, N,
        nullptr, nullptr, nullptr, nullptr, nullptr, 0);

    // ---- prop step 1 (2-pass aggregate, conv + combine -> out) ----
    aggregate_half<0><<<WB, 256, 0, stream>>>(row_start, csr_col, dis, deg_inv, h0, hbfA,
                                              agg_hi, agg_lo, N);
    aggregate_half<1><<<WB, 256, 0, stream>>>(row_start, csr_col, dis, deg_inv, h0, hbfB,
                                              agg_hi, agg_lo, N);
    gemm_ldsw<HF, 2, false><<<GBK, 256, 0, stream>>>(
        nullptr, agg_hi, agg_lo, fc, conv_b, out, nullptr, nullptr,
        h0, deg_inv, dis, root_emb, nullptr, nullptr, N,
        nullptr, nullptr, nullptr, nullptr, nullptr, 0);
}